// Round 1
// baseline (432.365 us; speedup 1.0000x reference)
//
#include <hip/hip_runtime.h>

// Problem: prediction [M=16,K=16,N=16,B=2048,C=10] fp32, label [B] int.
// out = mean over all slices of (argmax_c pred == label[b]).
// NSLICE = 8388608 slices of 10 contiguous floats (40 B). 336 MB read once.
//
// R5 theory: R4's direct 80-B-strided float4 loads are TA-transaction-bound
// (~40 cache lines touched per load instruction vs 8 for coalesced), putting
// eval_acc at ~200 us vs a ~53 us HBM floor. Fix: LDS-stage 20 KB/block with
// fully-coalesced global loads (each wave instr = 1024 contiguous bytes),
// then read slices back from LDS. The stride-5-float4 LDS read is
// conflict-free WITHOUT padding: bank-quad(i) = i%8 and 5t%8 is a bijection
// over 8 consecutive lanes (gcd(5,8)=1); write side t%8 likewise. LDS
// round-trip = 2x336 MB @ ~69 TB/s ~= 10 us, hidden under the HBM stream.

#define NSLICE (16 * 16 * 16 * 2048)
#define BATCH 2048
#define NCLS 10
#define TPB 256
#define NBLOCKS 16384  // 512 slices/block * 16384 = 8388608, exact

__global__ __launch_bounds__(TPB) void eval_acc(const float4* __restrict__ pred4,
                                                const int* __restrict__ label,
                                                int* __restrict__ partial) {
    __shared__ float4 tile[TPB * 5];  // 20 KB: 512 slices (1280 float4)

    const int t = threadIdx.x;
    const size_t gbase = (size_t)blockIdx.x * (TPB * 5);

    // Fully coalesced staging: wave reads 64 consecutive float4 per instr.
#pragma unroll
    for (int j = 0; j < 5; ++j)
        tile[t + TPB * j] = pred4[gbase + t + TPB * j];

    __syncthreads();

    // Conflict-free strided read-back: quad = (5t+m)%8 bijective per 8 lanes.
    const float4 v0 = tile[5 * t + 0];
    const float4 v1 = tile[5 * t + 1];
    const float4 v2 = tile[5 * t + 2];
    const float4 v3 = tile[5 * t + 3];
    const float4 v4 = tile[5 * t + 4];

    const int pair = blockIdx.x * TPB + t;  // this thread's slice pair (2p, 2p+1)
    const int b0 = (2 * pair) & (BATCH - 1);  // 2p even -> b1 = b0+1
    const int lab0 = label[b0];
    const int lab1 = label[b0 + 1];

    float f[20];
    f[0] = v0.x;  f[1] = v0.y;  f[2] = v0.z;  f[3] = v0.w;
    f[4] = v1.x;  f[5] = v1.y;  f[6] = v1.z;  f[7] = v1.w;
    f[8] = v2.x;  f[9] = v2.y;  f[10] = v2.z; f[11] = v2.w;
    f[12] = v3.x; f[13] = v3.y; f[14] = v3.z; f[15] = v3.w;
    f[16] = v4.x; f[17] = v4.y; f[18] = v4.z; f[19] = v4.w;

    int bi0 = 0;
    float m0 = f[0];
#pragma unroll
    for (int j = 1; j < NCLS; ++j)
        if (f[j] > m0) { m0 = f[j]; bi0 = j; }  // first-max wins, matches jnp
    int bi1 = 0;
    float m1 = f[NCLS];
#pragma unroll
    for (int j = 1; j < NCLS; ++j)
        if (f[NCLS + j] > m1) { m1 = f[NCLS + j]; bi1 = j; }

    int local = (bi0 == lab0) + (bi1 == lab1);

#pragma unroll
    for (int off = 32; off > 0; off >>= 1) local += __shfl_down(local, off, 64);

    __shared__ int wsum[4];
    const int w = threadIdx.x >> 6;
    if ((threadIdx.x & 63) == 0) wsum[w] = local;
    __syncthreads();
    if (threadIdx.x == 0)
        partial[blockIdx.x] = wsum[0] + wsum[1] + wsum[2] + wsum[3];
}

__global__ __launch_bounds__(1024) void eval_fin(const int* __restrict__ partial,
                                                 float* __restrict__ out) {
    __shared__ int wsum[16];
    const int w = threadIdx.x >> 6;
    const int lane = threadIdx.x & 63;

    int s = 0;
#pragma unroll
    for (int i = 0; i < NBLOCKS / 1024; ++i)  // 16 per thread, coalesced
        s += partial[i * 1024 + threadIdx.x];

#pragma unroll
    for (int off = 32; off > 0; off >>= 1) s += __shfl_down(s, off, 64);

    if (lane == 0) wsum[w] = s;
    __syncthreads();
    if (threadIdx.x == 0) {
        int total = 0;
#pragma unroll
        for (int i = 0; i < 16; ++i) total += wsum[i];
        // total <= 2^23 exactly representable; /2^23 exact
        out[0] = (float)total * (1.0f / (float)NSLICE);
    }
}

extern "C" void kernel_launch(void* const* d_in, const int* in_sizes, int n_in,
                              void* d_out, int out_size, void* d_ws, size_t ws_size,
                              hipStream_t stream) {
    const float4* pred4 = (const float4*)d_in[0];
    const int* label = (const int*)d_in[1];
    int* partial = (int*)d_ws;  // 16384 ints, fully overwritten before read
    float* out = (float*)d_out;

    eval_acc<<<NBLOCKS, TPB, 0, stream>>>(pred4, label, partial);
    eval_fin<<<1, 1024, 0, stream>>>(partial, out);
}